// Round 15
// baseline (141.617 us; speedup 1.0000x reference)
//
#include <hip/hip_runtime.h>
#include <cstdint>

// StreamNet K3 S1 halo conv, bf16 MFMA implicit-GEMM.
// R20 = R19 with the chain-geometry OOB bug fixed. R19 crashed: typ in 0..7
// was kept from 2-tile-chain geometry while chains were 4 tiles -> ty =
// 4*typ+t reached 31 (y=496 on a 256-row image), OOB out-writes, core dump.
// R20: chains of TWO vertically adjacent tiles -> 16cx x 8typ x 8b = 1024
// blocks (the proven 4-blk/CU grid), ty = 2*typ + t, t in {0,1}. Per-block
// work = R13's (two 16x16 = one 16x32), same overhead amortization, PLUS
// the loop keeps tile-1's 24 load insts in flight through tile-0's whole
// sweep (continuous read stream; R14/R15 never ran this at 4 blk/CU
// unhandicapped). Tile-1 top halo = tile-0 bottom rows (L1-hot).
// Keeps R19: lane-contiguous W image ([t][oh][lane][4dw] pack_w) -> Bf
// ds_read_b128 conflict-free; single X buffer + W region = 39168B LDS;
// prefetch split around the dr 0-2/3-5 sweep boundary (live set ~155);
// plain (256,2) only (R7/R10/R11: min-occupancy attrs -> RA squeeze+spill);
// XCD swizzle (batch i -> XCD i); plain f4 epilogue stores; b64 interior
// LDS stores; W-loads-before-X-loads (FIFO vmcnt).
//
// Padded input Xp[b][c][r][cc], r,cc in [0,258):
//   r < 2           -> bbuf[b][c][r][cc]           (bbuf [B][C][2][258])
//   r>=2, cc < 2    -> rbuf[b][c][r-2][cc]         (rbuf [B][C][256][2])
//   r>=2, cc>=2     -> (cc-2 == 255) ? 0 : x[b][c][r-2][cc-2]

constexpr int B  = 8;
constexpr int C  = 32;
constexpr int P  = 256;
constexpr int KB = 2;
constexpr int TS = 16;            // tile side
constexpr int RS = 18;            // LDS row stride (dwords) == padded width
constexpr int PL = 324;           // plane stride (dwords); A-reads 2-way, free
constexpr int XSZ = 16 * PL;      // 5184 dwords
constexpr int WOFF = XSZ;         // W region offset (4608 dwords)
constexpr int LDSZ = XSZ + 4608;  // 9792 dwords = 39168 B -> 4 blocks/CU

typedef short bf16x8 __attribute__((ext_vector_type(8)));
typedef float f32x4  __attribute__((ext_vector_type(4)));
union Frag { uint32_t u[4]; bf16x8 v; };

static __device__ __forceinline__ uint32_t pk_bf16(float lo, float hi) {
    uint32_t a  = __builtin_bit_cast(uint32_t, lo);
    uint32_t b2 = __builtin_bit_cast(uint32_t, hi);
    a  += 0x7FFFu + ((a  >> 16) & 1u);
    b2 += 0x7FFFu + ((b2 >> 16) & 1u);
    return (a >> 16) | (b2 & 0xFFFF0000u);
}

// ---- prologue: pack W -> LANE-CONTIGUOUS bf16-pair image in d_ws ----
// dword idx = t*512 + oh*256 + lane*4 + p holds pair(oc=oh*16+(lane&15),
// icpair=4*(lane>>4)+p, tap t): Bf ds_read_b128 is 16B x lane -> conflict-free.
__global__ __launch_bounds__(256) void pack_w_kernel(
    const float* __restrict__ W, uint32_t* __restrict__ wpk)
{
    const int idx = blockIdx.x * 256 + threadIdx.x;    // 0..4607
    const int t   = idx >> 9;
    const int r   = idx & 511;
    const int oh  = r >> 8;
    const int l   = (r >> 2) & 63;
    const int p   = r & 3;
    const int oc  = oh * 16 + (l & 15);
    const int icp = 4 * (l >> 4) + p;
    const float lo = W[(oc * C + 2 * icp) * 9 + t];
    const float hi = W[(oc * C + 2 * icp + 1) * 9 + t];
    wpk[idx] = pk_bf16(lo, hi);
}

struct St16 {                      // one plane-pair's staged data (16x16 tile)
    float4 a0, c0;                 // interior: lo plane, hi plane (4 cols/lane)
    float  h0l, h0h, h1l, h1h;     // 2 halo cells x (lo, hi)
};

__global__ __launch_bounds__(256, 2) void conv_mfma(
    const float* __restrict__ x,      // [B][C][P][P]
    const float* __restrict__ rbuf,   // [B][C][P][KB]
    const float* __restrict__ bbuf,   // [B][C][KB][P+KB]
    const uint32_t* __restrict__ wpk, // packed W image (4608 dwords)
    const float* __restrict__ bias,   // [C]
    float* __restrict__ out)          // [B][C][P][P]
{
    const int tid  = threadIdx.x;
    const int lane = tid & 63;
    const int w    = tid >> 6;        // wave 0..3
    const int q    = lane >> 4;
    const int n16  = lane & 15;

    // XCD swizzle: XCD i -> sw [128i,128(i+1)) = all tile-chains of batch i.
    const int sw  = (blockIdx.x & 7) * 128 + (blockIdx.x >> 3);
    const int b   = sw >> 7;          // 0..7
    const int cx  = (sw >> 3) & 15;   // 0..15
    const int typ = sw & 7;           // chain: tiles ty = 2*typ, 2*typ+1
    const int x0  = cx * TS;

    __shared__ uint32_t Xs[LDSZ];     // [0,5184) X tile; [5184,9792) W

    // ---- lane constants ----
    const int srow = lane >> 2;                 // 0..15
    const int scol = (lane & 3) * 4;            // 0,4,8,12
    const bool zc  = (cx == 15) && ((lane & 3) == 3);   // col 255 in .w

    // halo cells: 68 = top 2x18 (c 0..35) + left 16x2 (c 36..67)
    int prowA[2], pcolA[2], h_ldso[2];
    #pragma unroll
    for (int ci = 0; ci < 2; ++ci) {
        const int c = lane + 64 * ci;
        int prow, pcol;
        if (c < 36) { const int hr = (c >= 18) ? 1 : 0; prow = hr; pcol = c - 18 * hr; }
        else        { const int cc = c - 36; prow = KB + (cc >> 1); pcol = cc & 1; }
        prowA[ci] = prow; pcolA[ci] = pcol;
        h_ldso[ci] = prow * RS + pcol;
    }
    const bool h1a = lane < 4;                  // cell1 active

    const float* xb = x    + (size_t)b * C * P * P;
    const float* rb = rbuf + (size_t)b * C * P * KB;
    const float* bb = bbuf + (size_t)b * C * KB * (P + KB);
    const float* basep[3] = { xb, rb, bb };
    const int    psz[3]   = { P * P, P * KB, KB * (P + KB) };

    const float* h_bp[2]; int h_ps[2]; bool h_z[2];
    auto mkh = [&](int y0) {
        #pragma unroll
        for (int ci = 0; ci < 2; ++ci) {
            const int gr = y0 + prowA[ci], gc = x0 + pcolA[ci];
            int sel, off; bool zz = false;
            if (gr < KB)      { sel = 2; off = gr * (P + KB) + gc; }
            else if (gc < KB) { sel = 1; off = (gr - KB) * KB + gc; }
            else              { sel = 0; off = (gr - KB) * P + (gc - KB);
                                zz = (gc == P + KB - 1); }
            h_bp[ci] = basep[sel] + off;
            h_ps[ci] = psz[sel];
            h_z[ci]  = zz;
        }
    };

    auto ldk = [&](int k2, int y0, St16& S) {
        const int m = 4 * k2 + w;
        const float* pi = xb + (size_t)(2 * m) * (P * P) + (y0 + srow) * P + x0 + scol;
        S.a0 = *(const float4*)pi;
        S.c0 = *(const float4*)(pi + P * P);
        const float* p0 = h_bp[0] + (size_t)(2 * m) * h_ps[0];
        S.h0l = h_z[0] ? 0.f : p0[0];
        S.h0h = h_z[0] ? 0.f : p0[h_ps[0]];
        if (h1a) {
            const float* p1 = h_bp[1] + (size_t)(2 * m) * h_ps[1];
            S.h1l = h_z[1] ? 0.f : p1[0];
            S.h1h = h_z[1] ? 0.f : p1[h_ps[1]];
        }
    };

    auto stk = [&](int k2, const St16& S) {
        const int m = 4 * k2 + w;
        float4 a0 = S.a0, c0 = S.c0;
        if (zc) { a0.w = 0.f; c0.w = 0.f; }
        uint2 p0, p1;
        p0.x = pk_bf16(a0.x, c0.x); p0.y = pk_bf16(a0.y, c0.y);
        p1.x = pk_bf16(a0.z, c0.z); p1.y = pk_bf16(a0.w, c0.w);
        uint32_t* base = Xs + m * PL + (srow + KB) * RS + KB + scol;  // 8B aligned
        *(uint2*)(base + 0) = p0;
        *(uint2*)(base + 2) = p1;
        Xs[m * PL + h_ldso[0]] = pk_bf16(S.h0l, S.h0h);
        if (h1a) Xs[m * PL + h_ldso[1]] = pk_bf16(S.h1l, S.h1h);
    };

    // ---- prologue: W loads FIRST, then T0 X loads, W->LDS, stage T0 ----
    const uint4* wp4 = (const uint4*)wpk;          // 1152 uint4
    uint4 wv0 = wp4[tid];
    uint4 wv1 = wp4[256 + tid];
    uint4 wv2 = wp4[512 + tid];
    uint4 wv3 = wp4[768 + tid];
    uint4 wvt;
    const bool wtail = tid < 128;
    if (wtail) wvt = wp4[1024 + tid];

    St16 Sn[4];
    mkh(2 * typ * TS);
    #pragma unroll
    for (int k2 = 0; k2 < 4; ++k2) ldk(k2, 2 * typ * TS, Sn[k2]);

    uint4* xsW = (uint4*)(Xs + WOFF);
    xsW[tid]       = wv0;
    xsW[256 + tid] = wv1;
    xsW[512 + tid] = wv2;
    xsW[768 + tid] = wv3;
    if (wtail) xsW[1024 + tid] = wvt;

    #pragma unroll
    for (int k2 = 0; k2 < 4; ++k2) stk(k2, Sn[k2]);

    const float bv0 = bias[n16];
    const float bv1 = bias[16 + n16];
    __syncthreads();               // W region + tile 0 visible

    // ---- tile loop: compute t while prefetching t+1 ----
    #pragma unroll 1
    for (int t = 0; t < 2; ++t) {
        const int y0 = (2 * typ + t) * TS;

        // prefetch first half of tile t+1 (in flight through the sweep)
        if (t < 1) {
            mkh(y0 + TS);
            ldk(0, y0 + TS, Sn[0]);
            ldk(1, y0 + TS, Sn[1]);
        }

        // Bf from LDS, lane-contiguous -> conflict-free b128 reads
        Frag Bf[9][2];
        #pragma unroll
        for (int tt = 0; tt < 9; ++tt)
            #pragma unroll
            for (int oh = 0; oh < 2; ++oh)
                *(uint4*)Bf[tt][oh].u =
                    *(const uint4*)&Xs[WOFF + tt * 512 + oh * 256 + lane * 4];

        f32x4 acc[4][2];
        #pragma unroll
        for (int rr = 0; rr < 4; ++rr)
            #pragma unroll
            for (int oh = 0; oh < 2; ++oh)
                #pragma unroll
                for (int e = 0; e < 4; ++e) acc[rr][oh][e] = 0.f;

        // A-frags deduped: padded row 4w+dr serves all (rr,ky) with rr+ky==dr
        #pragma unroll
        for (int dr = 0; dr < 3; ++dr) {
            Frag A[3];
            const uint32_t* ap = Xs + (4 * q) * PL + (4 * w + dr) * RS + n16;
            #pragma unroll
            for (int kx = 0; kx < 3; ++kx)
                #pragma unroll
                for (int p = 0; p < 4; ++p)
                    A[kx].u[p] = ap[p * PL + kx];
            #pragma unroll
            for (int ky = 0; ky < 3; ++ky) {
                const int rr = dr - ky;
                if (rr >= 0 && rr < 4) {
                    #pragma unroll
                    for (int kx = 0; kx < 3; ++kx) {
                        acc[rr][0] = __builtin_amdgcn_mfma_f32_16x16x32_bf16(
                                         A[kx].v, Bf[ky * 3 + kx][0].v, acc[rr][0], 0, 0, 0);
                        acc[rr][1] = __builtin_amdgcn_mfma_f32_16x16x32_bf16(
                                         A[kx].v, Bf[ky * 3 + kx][1].v, acc[rr][1], 0, 0, 0);
                    }
                }
            }
        }

        // prefetch second half of tile t+1
        if (t < 1) {
            ldk(2, y0 + TS, Sn[2]);
            ldk(3, y0 + TS, Sn[3]);
        }

        #pragma unroll
        for (int dr = 3; dr < 6; ++dr) {
            Frag A[3];
            const uint32_t* ap = Xs + (4 * q) * PL + (4 * w + dr) * RS + n16;
            #pragma unroll
            for (int kx = 0; kx < 3; ++kx)
                #pragma unroll
                for (int p = 0; p < 4; ++p)
                    A[kx].u[p] = ap[p * PL + kx];
            #pragma unroll
            for (int ky = 0; ky < 3; ++ky) {
                const int rr = dr - ky;
                if (rr >= 0 && rr < 4) {
                    #pragma unroll
                    for (int kx = 0; kx < 3; ++kx) {
                        acc[rr][0] = __builtin_amdgcn_mfma_f32_16x16x32_bf16(
                                         A[kx].v, Bf[ky * 3 + kx][0].v, acc[rr][0], 0, 0, 0);
                        acc[rr][1] = __builtin_amdgcn_mfma_f32_16x16x32_bf16(
                                         A[kx].v, Bf[ky * 3 + kx][1].v, acc[rr][1], 0, 0, 0);
                    }
                }
            }
        }

        // epilogue: plain float4 stores (L2 write combining)
        #pragma unroll
        for (int oh = 0; oh < 2; ++oh) {
            const int oc = oh * 16 + n16;
            const float bv = oh ? bv1 : bv0;
            #pragma unroll
            for (int rr = 0; rr < 4; ++rr) {
                float4 v;
                v.x = acc[rr][oh][0] + bv;
                v.y = acc[rr][oh][1] + bv;
                v.z = acc[rr][oh][2] + bv;
                v.w = acc[rr][oh][3] + bv;
                *(float4*)&out[((size_t)(b * C + oc) * P + (y0 + 4 * w + rr)) * P
                               + x0 + 4 * q] = v;
            }
        }

        __syncthreads();           // all waves done reading Xs (tile t)
        if (t < 1) {
            #pragma unroll
            for (int k2 = 0; k2 < 4; ++k2) stk(k2, Sn[k2]);
        }
        __syncthreads();           // tile t+1 visible for next iteration
    }
}

extern "C" void kernel_launch(void* const* d_in, const int* in_sizes, int n_in,
                              void* d_out, int out_size, void* d_ws, size_t ws_size,
                              hipStream_t stream) {
    const float* x    = (const float*)d_in[0];
    const float* rbuf = (const float*)d_in[1];
    const float* bbuf = (const float*)d_in[2];
    const float* W    = (const float*)d_in[3];
    const float* bias = (const float*)d_in[4];
    float* out = (float*)d_out;
    uint32_t* wpk = (uint32_t*)d_ws;              // 18432 B used

    pack_w_kernel<<<18, 256, 0, stream>>>(W, wpk);
    conv_mfma<<<1024, 256, 0, stream>>>(x, rbuf, bbuf, wpk, bias, out);
}